// Round 15
// baseline (12299.178 us; speedup 1.0000x reference)
//
#include <hip/hip_runtime.h>

#define BB 16
#define SS 256
#define NVOCAB 32000
#define NEMB 300
#define NT 384

typedef float f4_t __attribute__((ext_vector_type(4)));
typedef unsigned int u4_t __attribute__((ext_vector_type(4)));
typedef short bf16x8 __attribute__((ext_vector_type(8)));
typedef float f32x4 __attribute__((ext_vector_type(4)));
typedef unsigned short ushort_t;

// unaligned-safe float4 global load
__device__ __forceinline__ f4_t load_f4u(const float* p) {
    f4_t v;
    __builtin_memcpy(&v, p, sizeof(f4_t));
    return v;
}

// LLC-coherent publish: 16B store (value+tag atomic at LLC) + drain inside asm
__device__ __forceinline__ void llc_store_u4_drain(u4_t* p, u4_t v) {
    asm volatile("global_store_dwordx4 %0, %1, off sc0 sc1\n\t"
                 "s_waitcnt vmcnt(0)" :: "v"(p), "v"(v) : "memory");
}

// Bundled coherent loads: 8 x dwordx4 issued and WAITED inside one asm block.
__device__ __forceinline__ void llc_load8_wait(
        u4_t& u0, u4_t& u1, u4_t& u2, u4_t& u3,
        u4_t& u4v, u4_t& u5v, u4_t& u6v, u4_t& u7v,
        const u4_t* p0, const u4_t* p1, const u4_t* p2, const u4_t* p3,
        const u4_t* p4, const u4_t* p5, const u4_t* p6, const u4_t* p7) {
    asm volatile(
        "global_load_dwordx4 %0, %8, off sc0 sc1\n\t"
        "global_load_dwordx4 %1, %9, off sc0 sc1\n\t"
        "global_load_dwordx4 %2, %10, off sc0 sc1\n\t"
        "global_load_dwordx4 %3, %11, off sc0 sc1\n\t"
        "global_load_dwordx4 %4, %12, off sc0 sc1\n\t"
        "global_load_dwordx4 %5, %13, off sc0 sc1\n\t"
        "global_load_dwordx4 %6, %14, off sc0 sc1\n\t"
        "global_load_dwordx4 %7, %15, off sc0 sc1\n\t"
        "s_waitcnt vmcnt(0)"
        : "=&v"(u0), "=&v"(u1), "=&v"(u2), "=&v"(u3),
          "=&v"(u4v), "=&v"(u5v), "=&v"(u6v), "=&v"(u7v)
        : "v"(p0), "v"(p1), "v"(p2), "v"(p3),
          "v"(p4), "v"(p5), "v"(p6), "v"(p7)
        : "memory");
}

// Stage 16 "rows" (batch items) x 1 chunk-col per thread: two 8-bundles with
// whole-8 parallel retry (r10-proven). dst[b][3t..3t+2] = chunk floats.
__device__ __forceinline__ void stage16rows(const u4_t* base, int rstr, unsigned tgt,
                                            float* dst, int dstr, int t) {
    const u4_t* cb = base + t;
    #pragma unroll
    for (int rh = 0; rh < 2; rh++) {
        const u4_t* q0 = cb + (rh * 8 + 0) * rstr;
        const u4_t* q1 = cb + (rh * 8 + 1) * rstr;
        const u4_t* q2 = cb + (rh * 8 + 2) * rstr;
        const u4_t* q3 = cb + (rh * 8 + 3) * rstr;
        const u4_t* q4 = cb + (rh * 8 + 4) * rstr;
        const u4_t* q5 = cb + (rh * 8 + 5) * rstr;
        const u4_t* q6 = cb + (rh * 8 + 6) * rstr;
        const u4_t* q7 = cb + (rh * 8 + 7) * rstr;
        u4_t u0, u1, u2, u3, u4v, u5v, u6v, u7v;
        for (;;) {
            llc_load8_wait(u0, u1, u2, u3, u4v, u5v, u6v, u7v,
                           q0, q1, q2, q3, q4, q5, q6, q7);
            int ok = (u0.w >= tgt) & (u1.w >= tgt) & (u2.w >= tgt) & (u3.w >= tgt)
                   & (u4v.w >= tgt) & (u5v.w >= tgt) & (u6v.w >= tgt) & (u7v.w >= tgt);
            if (ok) break;
        }
        float* d;
        d = dst + (rh * 8 + 0) * dstr + 3 * t;
        d[0] = __uint_as_float(u0.x); d[1] = __uint_as_float(u0.y); d[2] = __uint_as_float(u0.z);
        d = dst + (rh * 8 + 1) * dstr + 3 * t;
        d[0] = __uint_as_float(u1.x); d[1] = __uint_as_float(u1.y); d[2] = __uint_as_float(u1.z);
        d = dst + (rh * 8 + 2) * dstr + 3 * t;
        d[0] = __uint_as_float(u2.x); d[1] = __uint_as_float(u2.y); d[2] = __uint_as_float(u2.z);
        d = dst + (rh * 8 + 3) * dstr + 3 * t;
        d[0] = __uint_as_float(u3.x); d[1] = __uint_as_float(u3.y); d[2] = __uint_as_float(u3.z);
        d = dst + (rh * 8 + 4) * dstr + 3 * t;
        d[0] = __uint_as_float(u4v.x); d[1] = __uint_as_float(u4v.y); d[2] = __uint_as_float(u4v.z);
        d = dst + (rh * 8 + 5) * dstr + 3 * t;
        d[0] = __uint_as_float(u5v.x); d[1] = __uint_as_float(u5v.y); d[2] = __uint_as_float(u5v.z);
        d = dst + (rh * 8 + 6) * dstr + 3 * t;
        d[0] = __uint_as_float(u6v.x); d[1] = __uint_as_float(u6v.y); d[2] = __uint_as_float(u6v.z);
        d = dst + (rh * 8 + 7) * dstr + 3 * t;
        d[0] = __uint_as_float(u7v.x); d[1] = __uint_as_float(u7v.y); d[2] = __uint_as_float(u7v.z);
    }
}

// 8-wide k sub-phase: 3 W rows x 16 b FMA into a[3][16]. W cols clamped to klim
// (reads col 0 when out of range; ht pad there is 0 so product is 0).
__device__ __forceinline__ void fma_sub(float (&a)[3][16],
                                        const float* w0, const float* w1, const float* w2,
                                        int kk, int klim, const float* hbase, int ldh) {
    const int k0 = (kk < klim) ? kk : 0;
    const int k1 = (kk + 4 < klim) ? (kk + 4) : 0;
    const f4_t w00 = load_f4u(w0 + k0), w01 = load_f4u(w0 + k1);
    const f4_t w10 = load_f4u(w1 + k0), w11 = load_f4u(w1 + k1);
    const f4_t w20 = load_f4u(w2 + k0), w21 = load_f4u(w2 + k1);
    const float* hb = hbase + kk;
    #pragma unroll
    for (int b = 0; b < 16; b++) {
        const f4_t h0v = *reinterpret_cast<const f4_t*>(hb + b * ldh);
        const f4_t h1v = *reinterpret_cast<const f4_t*>(hb + b * ldh + 4);
        float acc;
        acc = a[0][b];
        acc = fmaf(w00.x, h0v.x, acc); acc = fmaf(w00.y, h0v.y, acc);
        acc = fmaf(w00.z, h0v.z, acc); acc = fmaf(w00.w, h0v.w, acc);
        acc = fmaf(w01.x, h1v.x, acc); acc = fmaf(w01.y, h1v.y, acc);
        acc = fmaf(w01.z, h1v.z, acc); acc = fmaf(w01.w, h1v.w, acc);
        a[0][b] = acc;
        acc = a[1][b];
        acc = fmaf(w10.x, h0v.x, acc); acc = fmaf(w10.y, h0v.y, acc);
        acc = fmaf(w10.z, h0v.z, acc); acc = fmaf(w10.w, h0v.w, acc);
        acc = fmaf(w11.x, h1v.x, acc); acc = fmaf(w11.y, h1v.y, acc);
        acc = fmaf(w11.z, h1v.z, acc); acc = fmaf(w11.w, h1v.w, acc);
        a[1][b] = acc;
        acc = a[2][b];
        acc = fmaf(w20.x, h0v.x, acc); acc = fmaf(w20.y, h0v.y, acc);
        acc = fmaf(w20.z, h0v.z, acc); acc = fmaf(w20.w, h0v.w, acc);
        acc = fmaf(w21.x, h1v.x, acc); acc = fmaf(w21.y, h1v.y, acc);
        acc = fmaf(w21.z, h1v.z, acc); acc = fmaf(w21.w, h1v.w, acc);
        a[2][b] = acc;
    }
}

// full-wave butterfly reduce over the 8 k-slices in this wave; lane<8 writes
// rows (3*lane+j) of the 24-row pass into pbuf[wv][row*17 + b].
__device__ __forceinline__ void reduce_wave(float (&a)[3][16], float* pbuf,
                                            int wv, int lane, int PSS) {
    #pragma unroll
    for (int j = 0; j < 3; j++)
        #pragma unroll
        for (int b = 0; b < 16; b++) {
            float v = a[j][b];
            v += __shfl_xor(v, 8);
            v += __shfl_xor(v, 16);
            v += __shfl_xor(v, 32);
            if (lane < 8)
                pbuf[wv * PSS + (3 * lane + j) * 17 + b] = v;
        }
}

// ============================ embedding ============================
__global__ void embed_kernel(const int* __restrict__ ids,
                             const float* __restrict__ emb,
                             float* __restrict__ x0) {
    int bs = blockIdx.x;
    int id = ids[bs];
    const float* row = emb + (size_t)id * NEMB;
    float* out = x0 + (size_t)bs * NEMB;
    const float scale = 17.320508075688772f;   // sqrt(300)
    for (int e = threadIdx.x; e < NEMB; e += blockDim.x)
        out[e] = row[e] * scale;
}

// ============================ fp32 -> bf16 hi/lo split (RN), padded ============================
__global__ void conv_split(const float* __restrict__ src,
                           ushort_t* __restrict__ hi, ushort_t* __restrict__ lo,
                           int N, int K, int KP, int total) {
    for (int i = blockIdx.x * blockDim.x + threadIdx.x; i < total;
         i += gridDim.x * blockDim.x) {
        int r = i / KP, k = i - r * KP;
        float v = (r < N && k < K) ? src[(size_t)r * K + k] : 0.f;
        unsigned u = __float_as_uint(v);
        unsigned hb = (u + 0x7FFFu + ((u >> 16) & 1u)) >> 16;
        float hf = __uint_as_float(hb << 16);
        float rem = v - hf;
        unsigned u2 = __float_as_uint(rem);
        unsigned lb = (u2 + 0x7FFFu + ((u2 >> 16) & 1u)) >> 16;
        hi[i] = (ushort_t)hb;
        lo[i] = (ushort_t)lb;
    }
}

// ============================ bf16-split MFMA GEMM ============================
__global__ __launch_bounds__(256) void gemm_mfma(
        const ushort_t* __restrict__ Ah, const ushort_t* __restrict__ Al,
        const ushort_t* __restrict__ Wh, const ushort_t* __restrict__ Wl,
        float* __restrict__ C, int N, int KP,
        const float* __restrict__ bias_i, const float* __restrict__ bias_h,
        int permuted) {
    constexpr int LD = 40;
    __shared__ ushort_t sA[2][128 * LD];
    __shared__ ushort_t sW[2][128 * LD];
    const int t    = threadIdx.x;
    const int lane = t & 63;
    const int wave = t >> 6;
    const int wm   = wave >> 1, wn = wave & 1;
    const int n0   = blockIdx.x * 128;
    const int m0   = blockIdx.y * 128;

    f32x4 acc[4][4];
    #pragma unroll
    for (int i = 0; i < 4; i++)
        #pragma unroll
        for (int j = 0; j < 4; j++)
            acc[i][j] = (f32x4){0.f, 0.f, 0.f, 0.f};

    const int nkt = KP >> 5;
    for (int kt = 0; kt < nkt; kt++) {
        __syncthreads();
        #pragma unroll
        for (int c = 0; c < 2; c++) {
            int id = t + c * 256;
            int r = id >> 2, kq = id & 3;
            int so = r * LD + kq * 8;
            size_t goA = (size_t)(m0 + r) * KP + kt * 32 + kq * 8;
            size_t goW = (size_t)(n0 + r) * KP + kt * 32 + kq * 8;
            *reinterpret_cast<u4_t*>(&sA[0][so]) = *reinterpret_cast<const u4_t*>(Ah + goA);
            *reinterpret_cast<u4_t*>(&sA[1][so]) = *reinterpret_cast<const u4_t*>(Al + goA);
            *reinterpret_cast<u4_t*>(&sW[0][so]) = *reinterpret_cast<const u4_t*>(Wh + goW);
            *reinterpret_cast<u4_t*>(&sW[1][so]) = *reinterpret_cast<const u4_t*>(Wl + goW);
        }
        __syncthreads();

        bf16x8 ah[4], al[4], wh[4], wl[4];
        #pragma unroll
        for (int i = 0; i < 4; i++) {
            int ro = (wm * 64 + i * 16 + (lane & 15)) * LD + (lane >> 4) * 8;
            int co = (wn * 64 + i * 16 + (lane & 15)) * LD + (lane >> 4) * 8;
            ah[i] = *reinterpret_cast<const bf16x8*>(&sA[0][ro]);
            al[i] = *reinterpret_cast<const bf16x8*>(&sA[1][ro]);
            wh[i] = *reinterpret_cast<const bf16x8*>(&sW[0][co]);
            wl[i] = *reinterpret_cast<const bf16x8*>(&sW[1][co]);
        }
        #pragma unroll
        for (int i = 0; i < 4; i++)
            #pragma unroll
            for (int j = 0; j < 4; j++) {
                acc[i][j] = __builtin_amdgcn_mfma_f32_16x16x32_bf16(ah[i], wh[j], acc[i][j], 0, 0, 0);
                acc[i][j] = __builtin_amdgcn_mfma_f32_16x16x32_bf16(ah[i], wl[j], acc[i][j], 0, 0, 0);
                acc[i][j] = __builtin_amdgcn_mfma_f32_16x16x32_bf16(al[i], wh[j], acc[i][j], 0, 0, 0);
            }
    }

    #pragma unroll
    for (int i = 0; i < 4; i++) {
        int row = m0 + wm * 64 + i * 16 + ((lane >> 4) << 2);
        #pragma unroll
        for (int j = 0; j < 4; j++) {
            int col = n0 + wn * 64 + j * 16 + (lane & 15);
            if (col < N) {
                float bv = bias_i ? (bias_i[col] + bias_h[col]) : 0.f;
                #pragma unroll
                for (int r2 = 0; r2 < 4; r2++) {
                    int m = row + r2;
                    float v = acc[i][j][r2] + bv;
                    size_t idx;
                    if (permuted) {
                        int b_ = m >> 8;
                        int s_ = m & 255;
                        idx = ((size_t)s_ * BB + b_) * (size_t)N + col;
                    } else {
                        idx = (size_t)m * (size_t)N + col;
                    }
                    C[idx] = v;
                }
            }
        }
    }
}

// ============================ fused 3-layer pipelined recurrence ============================
// 242 blocks, all co-resident (1/CU forced by LDS). Blocks 0-95: L0 (CHUNK=12),
// 96-191: L1 (CHUNK=12, input projection W_ih1 computed in-kernel from h0),
// 192-241: L2 (CHUNK=6). Cross/intra-layer h transported via once-written
// [s]-indexed tagged 16B chunks {h0,h1,h2,tag=s+1}; buffers zeroed per launch.
// L0 depends only on L0 -> runs ahead; L1 paces the pipeline; L2 trails 1 slot.

// ---- L0: h0[s] = lstm(xg0[s], h0[s-1]) ----
__device__ void rec_l0(float* lds, int t, int blk,
                       const float* __restrict__ Whh0,
                       const float* __restrict__ xg0,
                       u4_t* __restrict__ h0b) {
    float* ht   = lds;                   // [16][1152]
    float* pbuf = ht + 16 * 1152;        // [6][412]
    float* gbuf = pbuf + 6 * 412;        // [768]
    float* cbuf = gbuf + 768;            // [192]
    float* hlx  = cbuf + 192;            // [192]
    const int lane = t & 63, wv = t >> 6, ks = t >> 3, rg = t & 7;
    const int h0 = blk * 12;

    const float* wr[2][3];
    #pragma unroll
    for (int p = 0; p < 2; p++)
        #pragma unroll
        for (int j = 0; j < 3; j++) {
            int r = 24 * p + 3 * rg + j;
            int g = r / 12, l = r - g * 12;
            int lc = ((h0 + l) < 1150) ? l : 0;
            wr[p][j] = Whh0 + (size_t)(g * 1150 + h0 + lc) * 1150;
        }
    // xg pointers for this thread's two outputs
    const int r0 = t >> 4, b0 = t & 15;
    const float* xgp[2];
    #pragma unroll
    for (int p = 0; p < 2; p++) {
        int r = 24 * p + r0;
        int g = r / 12, l = r - g * 12;
        int lc = ((h0 + l) < 1150) ? l : 0;
        xgp[p] = xg0 + (size_t)b0 * 4600 + (g * 1150 + h0 + lc);
    }

    for (int i = t; i < 16 * 1152; i += NT) ht[i] = 0.f;
    if (t < 192) cbuf[t] = 0.f;
    __syncthreads();

    for (int s = 0; s < SS; s++) {
        float xgv0 = xgp[0][(size_t)s * 73600];
        float xgv1 = xgp[1][(size_t)s * 73600];
        if (s > 0)
            stage16rows(h0b + (size_t)(s - 1) * 6144, 384, (unsigned)s, ht, 1152, t);
        __syncthreads();

        #pragma unroll
        for (int p = 0; p < 2; p++) {
            float a[3][16];
            #pragma unroll
            for (int j = 0; j < 3; j++)
                #pragma unroll
                for (int b = 0; b < 16; b++) a[j][b] = 0.f;
            if (s > 0) {
                #pragma unroll
                for (int sub = 0; sub < 3; sub++)
                    fma_sub(a, wr[p][0], wr[p][1], wr[p][2],
                            ks * 24 + sub * 8, 1150, ht, 1152);
            }
            reduce_wave(a, pbuf, wv, lane, 412);
            __syncthreads();
            {
                float dot = (p == 0) ? xgv0 : xgv1;
                #pragma unroll
                for (int w = 0; w < 6; w++)
                    dot += pbuf[w * 412 + r0 * 17 + b0];
                gbuf[t + p * 384] = dot;
            }
            __syncthreads();
        }

        if (t < 192) {
            int l = t >> 4, b = t & 15;
            float gi = gbuf[(0 * 12 + l) * 16 + b];
            float gf = gbuf[(1 * 12 + l) * 16 + b];
            float gg = gbuf[(2 * 12 + l) * 16 + b];
            float go = gbuf[(3 * 12 + l) * 16 + b];
            float iv = 1.f / (1.f + expf(-gi));
            float fv = 1.f / (1.f + expf(-gf));
            float gv = tanhf(gg);
            float ov = 1.f / (1.f + expf(-go));
            float c = fv * cbuf[t] + iv * gv;
            cbuf[t] = c;
            float hv = ov * tanhf(c);
            hv = ((h0 + l) < 1150) ? hv : 0.f;
            hlx[b * 12 + l] = hv;
        }
        __syncthreads();

        if (t < 64) {
            int b = t >> 2, cj = t & 3;
            u4_t pk;
            pk.x = __float_as_uint(hlx[b * 12 + 3 * cj + 0]);
            pk.y = __float_as_uint(hlx[b * 12 + 3 * cj + 1]);
            pk.z = __float_as_uint(hlx[b * 12 + 3 * cj + 2]);
            pk.w = (unsigned)(s + 1);
            llc_store_u4_drain(h0b + (size_t)(s * 16 + b) * 384 + (blk * 4 + cj), pk);
        }
    }
}

// ---- L1: h1[s] = lstm(Wih1·h0[s] + b, h1[s-1]) ----
__device__ void rec_l1(float* lds, int t, int blk,
                       const float* __restrict__ Wih1,
                       const float* __restrict__ Whh1,
                       const float* __restrict__ bih1,
                       const float* __restrict__ bhh1,
                       const u4_t* __restrict__ h0b,
                       u4_t* __restrict__ h1b) {
    float* ht0  = lds;                   // [16][1152]
    float* ht1  = ht0 + 16 * 1152;       // [16][1152]
    float* pbuf = ht1 + 16 * 1152;       // [6][412]
    float* gbuf = pbuf + 6 * 412;        // [768]
    float* cbuf = gbuf + 768;            // [192]
    float* hlx  = cbuf + 192;            // [192]
    const int lane = t & 63, wv = t >> 6, ks = t >> 3, rg = t & 7;
    const int h0 = blk * 12;

    int nrow[2][3];
    #pragma unroll
    for (int p = 0; p < 2; p++)
        #pragma unroll
        for (int j = 0; j < 3; j++) {
            int r = 24 * p + 3 * rg + j;
            int g = r / 12, l = r - g * 12;
            int lc = ((h0 + l) < 1150) ? l : 0;
            nrow[p][j] = g * 1150 + h0 + lc;
        }
    const int r0 = t >> 4, b0 = t & 15;
    float bv[2];
    #pragma unroll
    for (int p = 0; p < 2; p++) {
        int r = 24 * p + r0;
        int g = r / 12, l = r - g * 12;
        int lc = ((h0 + l) < 1150) ? l : 0;
        int n = g * 1150 + h0 + lc;
        bv[p] = bih1[n] + bhh1[n];
    }

    for (int i = t; i < 2 * 16 * 1152; i += NT) ht0[i] = 0.f;
    if (t < 192) cbuf[t] = 0.f;
    __syncthreads();

    for (int s = 0; s < SS; s++) {
        stage16rows(h0b + (size_t)s * 6144, 384, (unsigned)(s + 1), ht0, 1152, t);
        if (s > 0)
            stage16rows(h1b + (size_t)(s - 1) * 6144, 384, (unsigned)s, ht1, 1152, t);
        __syncthreads();

        #pragma unroll
        for (int p = 0; p < 2; p++) {
            float a[3][16];
            #pragma unroll
            for (int j = 0; j < 3; j++)
                #pragma unroll
                for (int b = 0; b < 16; b++) a[j][b] = 0.f;
            const float* wi0 = Wih1 + (size_t)nrow[p][0] * 1150;
            const float* wi1 = Wih1 + (size_t)nrow[p][1] * 1150;
            const float* wi2 = Wih1 + (size_t)nrow[p][2] * 1150;
            #pragma unroll
            for (int sub = 0; sub < 3; sub++)
                fma_sub(a, wi0, wi1, wi2, ks * 24 + sub * 8, 1150, ht0, 1152);
            if (s > 0) {
                const float* wh0 = Whh1 + (size_t)nrow[p][0] * 1150;
                const float* wh1 = Whh1 + (size_t)nrow[p][1] * 1150;
                const float* wh2 = Whh1 + (size_t)nrow[p][2] * 1150;
                #pragma unroll
                for (int sub = 0; sub < 3; sub++)
                    fma_sub(a, wh0, wh1, wh2, ks * 24 + sub * 8, 1150, ht1, 1152);
            }
            reduce_wave(a, pbuf, wv, lane, 412);
            __syncthreads();
            {
                float dot = bv[p];
                #pragma unroll
                for (int w = 0; w < 6; w++)
                    dot += pbuf[w * 412 + r0 * 17 + b0];
                gbuf[t + p * 384] = dot;
            }
            __syncthreads();
        }

        if (t < 192) {
            int l = t >> 4, b = t & 15;
            float gi = gbuf[(0 * 12 + l) * 16 + b];
            float gf = gbuf[(1 * 12 + l) * 16 + b];
            float gg = gbuf[(2 * 12 + l) * 16 + b];
            float go = gbuf[(3 * 12 + l) * 16 + b];
            float iv = 1.f / (1.f + expf(-gi));
            float fv = 1.f / (1.f + expf(-gf));
            float gv = tanhf(gg);
            float ov = 1.f / (1.f + expf(-go));
            float c = fv * cbuf[t] + iv * gv;
            cbuf[t] = c;
            float hv = ov * tanhf(c);
            hv = ((h0 + l) < 1150) ? hv : 0.f;
            hlx[b * 12 + l] = hv;
        }
        __syncthreads();

        if (t < 64) {
            int b = t >> 2, cj = t & 3;
            u4_t pk;
            pk.x = __float_as_uint(hlx[b * 12 + 3 * cj + 0]);
            pk.y = __float_as_uint(hlx[b * 12 + 3 * cj + 1]);
            pk.z = __float_as_uint(hlx[b * 12 + 3 * cj + 2]);
            pk.w = (unsigned)(s + 1);
            llc_store_u4_drain(h1b + (size_t)(s * 16 + b) * 384 + (blk * 4 + cj), pk);
        }
    }
}

// ---- L2: h2[s] = lstm(Wih2·h1[s] + b, h2[s-1]); writes xout ----
__device__ void rec_l2(float* lds, int t, int blk,
                       const float* __restrict__ Wih2,
                       const float* __restrict__ Whh2,
                       const float* __restrict__ bih2,
                       const float* __restrict__ bhh2,
                       const u4_t* __restrict__ h1b,
                       u4_t* __restrict__ h2b,
                       float* __restrict__ xout) {
    float* ht1  = lds;                   // [16][1152]
    float* ht2  = ht1 + 16 * 1152;       // [16][384]
    float* pbuf = ht2 + 16 * 384;        // [6][412]
    float* gbuf = pbuf + 6 * 412;        // [384]
    float* cbuf = gbuf + 384;            // [96]
    float* hlx  = cbuf + 96;             // [96]
    const int lane = t & 63, wv = t >> 6, ks = t >> 3, rg = t & 7;
    const int h0c = blk * 6;

    const float* wi[3];
    const float* wh[3];
    #pragma unroll
    for (int j = 0; j < 3; j++) {
        int r = 3 * rg + j;
        int g = r / 6, l = r - g * 6;
        int n = g * 300 + h0c + l;
        wi[j] = Wih2 + (size_t)n * 1150;
        wh[j] = Whh2 + (size_t)n * 300;
    }
    const int r0 = t >> 4, b0 = t & 15;
    float bv;
    {
        int g = r0 / 6, l = r0 - g * 6;
        int n = g * 300 + h0c + l;
        bv = bih2[n] + bhh2[n];
    }

    for (int i = t; i < 16 * 1152 + 16 * 384; i += NT) ht1[i] = 0.f;
    if (t < 96) cbuf[t] = 0.f;
    __syncthreads();

    for (int s = 0; s < SS; s++) {
        stage16rows(h1b + (size_t)s * 6144, 384, (unsigned)(s + 1), ht1, 1152, t);
        if (s > 0 && t < 100)
            stage16rows(h2b + (size_t)(s - 1) * 2048, 128, (unsigned)s, ht2, 384, t);
        __syncthreads();

        float a[3][16];
        #pragma unroll
        for (int j = 0; j < 3; j++)
            #pragma unroll
            for (int b = 0; b < 16; b++) a[j][b] = 0.f;
        #pragma unroll
        for (int sub = 0; sub < 3; sub++)
            fma_sub(a, wi[0], wi[1], wi[2], ks * 24 + sub * 8, 1150, ht1, 1152);
        if (s > 0)
            fma_sub(a, wh[0], wh[1], wh[2], ks * 8, 300, ht2, 384);
        reduce_wave(a, pbuf, wv, lane, 412);
        __syncthreads();
        {
            float dot = bv;
            #pragma unroll
            for (int w = 0; w < 6; w++)
                dot += pbuf[w * 412 + r0 * 17 + b0];
            gbuf[t] = dot;
        }
        __syncthreads();

        if (t < 96) {
            int l = t >> 4, b = t & 15;
            float gi = gbuf[(0 * 6 + l) * 16 + b];
            float gf = gbuf[(1 * 6 + l) * 16 + b];
            float gg = gbuf[(2 * 6 + l) * 16 + b];
            float go = gbuf[(3 * 6 + l) * 16 + b];
            float iv = 1.f / (1.f + expf(-gi));
            float fv = 1.f / (1.f + expf(-gf));
            float gv = tanhf(gg);
            float ov = 1.f / (1.f + expf(-go));
            float c = fv * cbuf[t] + iv * gv;
            cbuf[t] = c;
            float hv = ov * tanhf(c);
            hlx[b * 6 + l] = hv;
            xout[(size_t)(b * 256 + s) * 300 + h0c + l] = hv;
        }
        __syncthreads();

        if (t < 32) {
            int b = t >> 1, cj = t & 1;
            u4_t pk;
            pk.x = __float_as_uint(hlx[b * 6 + 3 * cj + 0]);
            pk.y = __float_as_uint(hlx[b * 6 + 3 * cj + 1]);
            pk.z = __float_as_uint(hlx[b * 6 + 3 * cj + 2]);
            pk.w = (unsigned)(s + 1);
            llc_store_u4_drain(h2b + (size_t)(s * 16 + b) * 128 + (blk * 2 + cj), pk);
        }
    }
}

__global__ __launch_bounds__(NT, 1) void lstm_fused(
        const float* __restrict__ Whh0, const float* __restrict__ xg0,
        const float* __restrict__ Wih1, const float* __restrict__ Whh1,
        const float* __restrict__ bih1, const float* __restrict__ bhh1,
        const float* __restrict__ Wih2, const float* __restrict__ Whh2,
        const float* __restrict__ bih2, const float* __restrict__ bhh2,
        u4_t* __restrict__ h0b, u4_t* __restrict__ h1b, u4_t* __restrict__ h2b,
        float* __restrict__ xout) {
    extern __shared__ __align__(16) float lds[];
    const int t = threadIdx.x;
    const int blk = blockIdx.x;
    if (blk < 96)
        rec_l0(lds, t, blk, Whh0, xg0, h0b);
    else if (blk < 192)
        rec_l1(lds, t, blk - 96, Wih1, Whh1, bih1, bhh1, h0b, h1b);
    else
        rec_l2(lds, t, blk - 192, Wih2, Whh2, bih2, bhh2, h1b, h2b, xout);
}

// ============================ launch ============================
extern "C" void kernel_launch(void* const* d_in, const int* in_sizes, int n_in,
                              void* d_out, int out_size, void* d_ws, size_t ws_size,
                              hipStream_t stream) {
    const int*   ids  = (const int*)d_in[0];
    const float* emb  = (const float*)d_in[1];
    const float* Wih0 = (const float*)d_in[2];
    const float* Whh0 = (const float*)d_in[3];
    const float* bih0 = (const float*)d_in[4];
    const float* bhh0 = (const float*)d_in[5];
    const float* Wih1 = (const float*)d_in[6];
    const float* Whh1 = (const float*)d_in[7];
    const float* bih1 = (const float*)d_in[8];
    const float* bhh1 = (const float*)d_in[9];
    const float* Wih2 = (const float*)d_in[10];
    const float* Whh2 = (const float*)d_in[11];
    const float* bih2 = (const float*)d_in[12];
    const float* bhh2 = (const float*)d_in[13];
    float* out = (float*)d_out;
    (void)in_sizes; (void)n_in; (void)out_size; (void)ws_size;

    // workspace layout (floats)
    float* ws  = (float*)d_ws;
    float* xA  = ws;                       // 1,228,800 (x0; later h2 out)
    float* xB  = xA + 1228800;             // 4,710,400 (final fAh/fAl)
    float* xg0 = xB + 4710400;             // 18,841,600 (L0 gates; later fWh/fWl)

    // d_out scratch: small conv buffers < 16MB; tagged h-buffers at +16MB
    ushort_t* sc  = (ushort_t*)d_out;
    ushort_t* tAh = sc;                               // [4096][320]
    ushort_t* tAl = tAh + (size_t)4096 * 320;
    ushort_t* W0h = tAl + (size_t)4096 * 320;         // [4608][320]
    ushort_t* W0l = W0h + (size_t)4608 * 320;
    u4_t* h0b = (u4_t*)((char*)d_out + ((size_t)16 << 20));   // [256][16][384]
    u4_t* h1b = h0b + (size_t)256 * 16 * 384;                 // [256][16][384]
    u4_t* h2b = h1b + (size_t)256 * 16 * 384;                 // [256][16][128]

    // final-projection splits (live after fused kernel)
    ushort_t* fAh = (ushort_t*)xB;                    // [4096][320]
    ushort_t* fAl = fAh + (size_t)4096 * 320;
    ushort_t* fWh = (ushort_t*)xg0;                   // [32000][320]
    ushort_t* fWl = fWh + (size_t)32000 * 320;

    // zero tag buffers (graph-captured, runs every replay before the rec)
    hipMemsetAsync(h0b, 0, ((size_t)256 * 16 * (384 + 384 + 128)) * 16, stream);

    // ---- L0 input projection: embed -> split -> MFMA GEMM -> xg0 ----
    conv_split<<<dim3(720), dim3(256), 0, stream>>>(Wih0, W0h, W0l, 4600, 300, 320, 4608 * 320);
    embed_kernel<<<dim3(BB * SS), dim3(256), 0, stream>>>(ids, emb, xA);
    conv_split<<<dim3(640), dim3(256), 0, stream>>>(xA, tAh, tAl, 4096, 300, 320, 4096 * 320);
    gemm_mfma<<<dim3(36, 32), dim3(256), 0, stream>>>(tAh, tAl, W0h, W0l, xg0,
                                                      4600, 320, bih0, bhh0, 1);

    // ---- fused pipelined 3-layer recurrence (242 blocks, 1/CU) ----
    const size_t ldsF = (size_t)(2 * 16 * 1152 + 6 * 412 + 768 + 192 + 192) * 4;  // 161,952
    lstm_fused<<<dim3(242), dim3(NT), ldsF, stream>>>(
        Whh0, xg0, Wih1, Whh1, bih1, bhh1, Wih2, Whh2, bih2, bhh2,
        h0b, h1b, h2b, xA);

    // ---- tied output projection ----
    conv_split<<<dim3(640), dim3(256), 0, stream>>>(xA, fAh, fAl, 4096, 300, 320, 4096 * 320);
    conv_split<<<dim3(2048), dim3(256), 0, stream>>>(emb, fWh, fWl, 32000, 300, 320, 32000 * 320);
    gemm_mfma<<<dim3(250, 32), dim3(256), 0, stream>>>(fAh, fAl, fWh, fWl, out,
                                                       NVOCAB, 320, nullptr, nullptr, 0);
}